// Round 1
// 277.326 us; speedup vs baseline: 1.2850x; 1.2850x over previous
//
#include <hip/hip_runtime.h>
#include <hip/hip_fp16.h>

// CTC-like forward scan. R12 = R11 rewritten in "G-space":
//   G_t[p] = G_{t-1}[p] + W_t[p] * G_{t-1}[p-1],  W = exp(x_i - x_4) = V/S
// with G[0] == 1 identically and prod(S) recovered as sum(x_4) in log space.
// This removes the per-step 8x mul-by-S, the F0*=S stay chain, and the
// per-window F0/M0 frame bookkeeping (was ~10 of ~35 VALU ops/step; the
// single wave per CU is issue-bound at VALUBusy 5.38/6.25 ceiling).
// W stored as f16 (10-bit mantissa, range e^+-9 fits): update written as
// fmaf(Fs, (float)f16, F) so the backend can fold extract+cvt into
// v_fma_mix_f32 (8 ops/step for all the math).
// Staging pipeline unchanged from R11 (scheduler-proof 8-row register
// windows, 4-chunk-ahead global_load_lds, empty-asm pins). Renorm every 8
// steps, down-only alignment, boundary via one v_mov_dpp wave_shr:1.

#define TT 4096
#define BB 64
#define PP 512
#define LN2F 0.69314718055994531f

typedef _Float16 half2_t __attribute__((ext_vector_type(2)));

__device__ __forceinline__ unsigned f16_bits(float f) {
    return (unsigned)__half_as_ushort(__float2half(f));   // v_cvt_f16_f32, RNE
}

// prepass: x[t][b][5] -> xq[t*64+b] = {f16W0|f16W1, f16W2|f16W3, f32 x4, 0}
// W_i = exp(x_i - x_4). Consecutive threads = consecutive b: 20B/lane reads,
// 16B/lane writes, coalesced both sides.
__global__ __launch_bounds__(256, 1)
void ctc_prepass(const float* __restrict__ x, uint4* __restrict__ xq) {
    int j = blockIdx.x * 256 + threadIdx.x;        // j = t*64 + b
    const float* r = x + (size_t)j * 5;
    float x0 = r[0], x1 = r[1], x2 = r[2], x3 = r[3], x4 = r[4];
    float w0 = fminf(__expf(x0 - x4), 65000.0f);   // clamp: f16 inf insurance
    float w1 = fminf(__expf(x1 - x4), 65000.0f);
    float w2 = fminf(__expf(x2 - x4), 65000.0f);
    float w3 = fminf(__expf(x3 - x4), 65000.0f);
    uint4 o;
    o.x = f16_bits(w0) | (f16_bits(w1) << 16);
    o.y = f16_bits(w2) | (f16_bits(w3) << 16);
    o.z = __float_as_uint(x4);
    o.w = 0u;
    xq[j] = o;
}

__device__ __forceinline__ void gload_lds16(const void* g, void* l) {
    auto gp = (const __attribute__((address_space(1))) void*)(uintptr_t)g;
    auto lp = (__attribute__((address_space(3))) void*)(uintptr_t)l;
    __builtin_amdgcn_global_load_lds(gp, lp, 16, 0, 0);
}

// lane n <- lane n-1 across the whole wave; lane 0 keeps old (overridden).
__device__ __forceinline__ int shl1w_i(int s) {
    return __builtin_amdgcn_update_dpp(s, s, 0x138 /*wave_shr:1*/, 0xF, 0xF, false);
}
__device__ __forceinline__ float shl1w_f(float s) {
    return __int_as_float(shl1w_i(__float_as_int(s)));
}

__global__ __launch_bounds__(64, 1)
void ctc_scan(const uint4* __restrict__ xq, const int* __restrict__ seqs,
              const int* __restrict__ seqlens, float* __restrict__ out) {
    __shared__ __align__(16) uint4 ring[512];      // 8 KB: 8 chunks x 64 rows
    __shared__ float garr[PP + 1];

    const int b = blockIdx.x;
    const int l = threadIdx.x;                     // 0..63
    const bool lane0 = (l == 0);

    // per-lane v_perm byte controls (same convention as bf16: value i at
    // bytes 2i,2i+1 of {row.y:row.x})
    unsigned ctrl[4];
#pragma unroll
    for (int k = 0; k < 4; ++k) {
        unsigned i0 = (unsigned)seqs[b * PP + 8 * l + 2 * k];
        unsigned i1 = (unsigned)seqs[b * PP + 8 * l + 2 * k + 1];
        ctrl[k] = (2 * i0) | ((2 * i0 + 1) << 8) | ((2 * i1) << 16) | ((2 * i1 + 1) << 24);
    }

    // xq row (t,b) at xq[t*64+b]; chunk c, lane l stages row t=c*64+l.
    const uint4* gsrc = xq + b;                    // + 64*t

    // ---- stage chunks 0..3 ----
#pragma unroll
    for (int c0 = 0; c0 < 4; ++c0)
        gload_lds16(gsrc + (size_t)(c0 * 64 + l) * 64, &ring[c0 * 64 + l]);
    asm volatile("s_waitcnt vmcnt(3)" ::: "memory");   // chunk 0 resident

    float F[8];                                    // G values, frame 2^M
#pragma unroll
    for (int i = 0; i < 8; ++i) F[i] = 0.0f;
    int M = 0;
    float logs = 0.0f;                             // sum of x_4 (nat log of prod S)

    uint4 wA[8], wB[8];
#pragma unroll
    for (int i = 0; i < 8; ++i) wA[i] = ring[i];   // window 0
    int nrow = 8;                                  // ring row of next window

    auto window = [&](uint4 (&cur)[8], uint4 (&nxt)[8]) {
        // ---- burst-load next window, pin above consumption ----
        const int rb = nrow & 511;
        nrow += 8;
#pragma unroll
        for (int i = 0; i < 8; ++i) nxt[i] = ring[rb + i];
        asm volatile("" ::: "memory");

        // ---- window bookkeeping: renorm + neighbor frame alignment ----
        float m = F[0];
#pragma unroll
        for (int i = 1; i < 8; ++i) m = fmaxf(m, F[i]);
        int e2 = ((__float_as_int(m) >> 23) & 0xFF) - 127;
        e2 = (m > 0.0f) ? e2 : 0;
        const int Mp = M + e2;                     // post-renorm frame
        const int Mlp = shl1w_i(Mp);               // neighbor's post-renorm frame
        // lane0's virtual left neighbor is G[0]=1 with frame 0
        int dl = (lane0 ? 0 : Mlp) - Mp;
        int dlc = dl > 0 ? dl : 0;                 // down-only self-squash
        const int Mnew = Mp + dlc;
        const int sh = Mnew - M;                   // >= 0
#pragma unroll
        for (int i = 0; i < 8; ++i) F[i] = ldexpf(F[i], -sh);
        M = Mnew;
        int dn = Mlp - M; dn = dn > 0 ? 0 : dn;
        const float sA   = ldexpf(1.0f, dn);       // neighbor -> my frame
        const float sAx  = lane0 ? 0.0f : sA;
        const float cfin = lane0 ? ldexpf(1.0f, -M) : 0.0f;  // G[0]=1 in my frame
        // (lane0: M >= 0 always -- pinned by dl = -Mp squash -- so no overflow)

        // ---- 8 steps: F[i] += Fs[i] * W[i]  (v_fma_mix-friendly) ----
#pragma unroll
        for (int u = 0; u < 8; ++u) {
            const uint4 row = cur[u];
            logs += __uint_as_float(row.z);
            unsigned p0 = __builtin_amdgcn_perm(row.y, row.x, ctrl[0]);
            unsigned p1 = __builtin_amdgcn_perm(row.y, row.x, ctrl[1]);
            unsigned p2 = __builtin_amdgcn_perm(row.y, row.x, ctrl[2]);
            unsigned p3 = __builtin_amdgcn_perm(row.y, row.x, ctrl[3]);
            const half2_t h0 = __builtin_bit_cast(half2_t, p0);
            const half2_t h1 = __builtin_bit_cast(half2_t, p1);
            const half2_t h2 = __builtin_bit_cast(half2_t, p2);
            const half2_t h3 = __builtin_bit_cast(half2_t, p3);

            const float Flr = shl1w_f(F[7]);       // 1 DPP: lane n <- n-1
            const float fin = fmaf(Flr, sAx, cfin);

            F[7] = fmaf(F[6], (float)h3.y, F[7]);
            F[6] = fmaf(F[5], (float)h3.x, F[6]);
            F[5] = fmaf(F[4], (float)h2.y, F[5]);
            F[4] = fmaf(F[3], (float)h2.x, F[4]);
            F[3] = fmaf(F[2], (float)h1.y, F[3]);
            F[2] = fmaf(F[1], (float)h1.x, F[2]);
            F[1] = fmaf(F[0], (float)h0.y, F[1]);
            F[0] = fmaf(fin,  (float)h0.x, F[0]);
        }
    };

#pragma unroll 1
    for (int c = 0; c < 64; ++c) {
        int cs = (c + 4 > 63) ? 63 : (c + 4);
        gload_lds16(gsrc + (size_t)(cs * 64 + l) * 64, &ring[((c + 4) & 7) * 64 + l]);
        asm volatile("s_waitcnt vmcnt(3)" ::: "memory");   // chunk c+1 resident

#pragma unroll 1
        for (int pr = 0; pr < 4; ++pr) {
            window(wA, wB);
            window(wB, wA);
        }
    }

    // ---- epilogue: log2 reconstruction (denormal-safe) ----
    const float lgS = logs * 1.44269504088896341f;  // log2(prod S)
#pragma unroll
    for (int i = 0; i < 8; ++i) {
        float v = fmaxf(F[i] * 16777216.0f, 1e-38f);
        garr[8 * l + 1 + i] = __log2f(v) - 24.0f + (float)M + lgS;
    }
    if (lane0) garr[0] = lgS;                       // position 0: log2(1) + lgS
    __syncthreads();
    if (lane0) {
        const int sl = seqlens[b];
        out[b] = -(garr[sl] * LN2F) / (float)TT;
    }
}

extern "C" void kernel_launch(void* const* d_in, const int* in_sizes, int n_in,
                              void* d_out, int out_size, void* d_ws, size_t ws_size,
                              hipStream_t stream) {
    const float* x       = (const float*)d_in[0];
    const int*   seqs    = (const int*)d_in[1];
    const int*   seqlens = (const int*)d_in[2];
    float*       out     = (float*)d_out;
    uint4*       xq      = (uint4*)d_ws;           // TT*BB rows x 16 B = 4 MB

    ctc_prepass<<<(TT * BB) / 256, 256, 0, stream>>>(x, xq);
    ctc_scan<<<BB, 64, 0, stream>>>(xq, seqs, seqlens, out);
}